// Round 18
// baseline (564.938 us; speedup 1.0000x reference)
//
#include <hip/hip_runtime.h>
#include <hip/hip_bf16.h>
#include <cstdint>
#include <cstddef>

// Problem constants (fixed by reference)
#define T_TOK 8192
#define DDIM  1024
#define FDIM  4096
#define NEXP  8
#define CAP   2048   // int(2.0 * T / E)

typedef __bf16 bf16_t;
typedef __bf16 bf16x8 __attribute__((ext_vector_type(8)));
typedef __bf16 bf16x4 __attribute__((ext_vector_type(4)));
typedef float  f32x4  __attribute__((ext_vector_type(4)));

// async global->LDS: lds dest must be WAVE-UNIFORM base; HW adds lane*16
__device__ __forceinline__ void gload16(const void* g, void* l) {
  __builtin_amdgcn_global_load_lds(
      (const __attribute__((address_space(1))) unsigned int*)g,
      (__attribute__((address_space(3))) unsigned int*)l,
      16, 0, 0);
}

#define VMWAIT(N) asm volatile("s_waitcnt vmcnt(" #N ")" ::: "memory")
#define BARR asm volatile("s_barrier" ::: "memory")

// ---- shared 128x128 transpose+convert tile body (PIPELINED halves) ----
// S[R][C] f32 -> D[C][R] bf16. All 16 float4 loads issued before the first LDS
// write. LDS swizzle: phys_col(r,c) = c ^ ((r>>5)<<2) -> phase2 read 2-way (free).
__device__ __forceinline__ void transpose_tile128(const float* __restrict__ s, bf16_t* __restrict__ d,
                                                  int R, int C, int bx, int by,
                                                  float (*tile)[65], int tid) {
  const int r0 = tid >> 4;
  const int c4 = (tid & 15) * 4;
  const int cq = tid >> 4;
  const int dk = (tid & 15) * 8;
  float4 v0[8], v1[8];
#pragma unroll
  for (int p = 0; p < 8; ++p)
    v0[p] = *(const float4*)&s[(size_t)(by + r0 + p * 16) * C + bx + c4];
#pragma unroll
  for (int p = 0; p < 8; ++p)          // half-2 loads issued early (held in regs)
    v1[p] = *(const float4*)&s[(size_t)(by + r0 + p * 16) * C + bx + 64 + c4];

  auto wr_lds = [&](float4* v) {
#pragma unroll
    for (int p = 0; p < 8; ++p) {
      int r = r0 + p * 16;
      int sw = (r >> 5) << 2;
      tile[r][(c4 + 0) ^ sw] = v[p].x; tile[r][(c4 + 1) ^ sw] = v[p].y;
      tile[r][(c4 + 2) ^ sw] = v[p].z; tile[r][(c4 + 3) ^ sw] = v[p].w;
    }
  };
  auto phase2 = [&](int ch0) {
#pragma unroll
    for (int q = 0; q < 4; ++q) {
      int c = cq + 16 * q;
      bf16x8 o;
#pragma unroll
      for (int j = 0; j < 8; ++j) {
        int r = dk + j;
        o[j] = (bf16_t)tile[r][c ^ ((r >> 5) << 2)];
      }
      *(bf16x8*)&d[(size_t)(ch0 + c) * R + by + dk] = o;
    }
  };

  wr_lds(v0);
  __syncthreads();
  phase2(bx);
  __syncthreads();
  wr_lds(v1);
  __syncthreads();
  phase2(bx + 64);
}

// ======== K1: router (blocks [0,nrouter)) + W1T transpose (rest) ========
__global__ void router_w1t_kernel(const float* __restrict__ x, const float* __restrict__ wsw,
                                  const float* __restrict__ bsw, int* __restrict__ routes,
                                  float* __restrict__ rpm, float* __restrict__ partial,
                                  bf16_t* __restrict__ xbf,
                                  const float* __restrict__ W1, bf16_t* __restrict__ W1T,
                                  int nrouter) {
  __shared__ float tile[128][65];
  const int bid = blockIdx.x;
  const int tid = threadIdx.x;
  if (bid >= nrouter) {
    const int tbid = bid - nrouter;
    const int z = tbid >> 8;
    const int rem = tbid & 255;
    transpose_tile128(W1 + (size_t)z * ((size_t)DDIM * FDIM),
                      W1T + (size_t)z * ((size_t)DDIM * FDIM),
                      DDIM, FDIM, (rem & 31) * 128, (rem >> 5) * 128, tile, tid);
  } else {
    const int rb = bid;
    const int wv = tid >> 6, lane = tid & 63;
    const int t = rb * 4 + wv;
    const float4* xr = (const float4*)(x + (size_t)t * DDIM);
    float4 xv[4];
    float a[8] = {0.f,0.f,0.f,0.f,0.f,0.f,0.f,0.f};
#pragma unroll
    for (int p = 0; p < 4; ++p) {
      xv[p] = xr[lane + p * 64];
#pragma unroll
      for (int j = 0; j < 4; ++j) {
        float v = ((const float*)&xv[p])[j];
        int d2 = (lane + p * 64) * 4 + j;
        const float4* wr = (const float4*)(wsw + d2 * 8);
        float4 w0 = wr[0], w1 = wr[1];
        a[0] += v * w0.x; a[1] += v * w0.y; a[2] += v * w0.z; a[3] += v * w0.w;
        a[4] += v * w1.x; a[5] += v * w1.y; a[6] += v * w1.z; a[7] += v * w1.w;
      }
    }
#pragma unroll
    for (int e = 0; e < 8; ++e) {
#pragma unroll
      for (int off = 32; off > 0; off >>= 1) a[e] += __shfl_xor(a[e], off);
      a[e] += bsw[e];
    }
    float m = a[0]; int arg = 0;
#pragma unroll
    for (int e = 1; e < 8; ++e) { if (a[e] > m) { m = a[e]; arg = e; } }
    float p8[8]; float s2 = 0.f;
#pragma unroll
    for (int e = 0; e < 8; ++e) { p8[e] = expf(a[e] - m); s2 += p8[e]; }
    float inv_s = 1.f / s2;   // = softmax max since p[arg]=1
    bf16_t* xbr = xbf + (size_t)t * DDIM;
#pragma unroll
    for (int p = 0; p < 4; ++p) {
      int i4 = lane + p * 64;
      bf16x4 hb;
      hb[0] = (bf16_t)xv[p].x; hb[1] = (bf16_t)xv[p].y;
      hb[2] = (bf16_t)xv[p].z; hb[3] = (bf16_t)xv[p].w;
      *(bf16x4*)(xbr + (size_t)i4 * 4) = hb;
    }
    float* pp = &tile[0][0];             // reuse LDS: [4][8]
    if (lane == 0) {
      routes[t] = arg;
      rpm[t] = inv_s;
#pragma unroll
      for (int e = 0; e < 8; ++e) pp[wv * 8 + e] = p8[e] * inv_s;
    }
    __syncthreads();
    if (tid < 8) {
      int e = tid;
      partial[(size_t)rb * 8 + e] = pp[0 + e] + pp[8 + e] + pp[16 + e] + pp[24 + e];
    }
  }
}

// ---- scan: PARALLEL prefix (Hillis-Steele over 256 thr x 8 experts) + dispatch + rps ----
__global__ void scan_kernel(const int* __restrict__ routes, int* __restrict__ inv,
                            int* __restrict__ counts_i, float* __restrict__ out_counts,
                            float* __restrict__ out_ndrop, int* __restrict__ drop_list,
                            int* __restrict__ ndrop_i, const float* __restrict__ partial,
                            float* __restrict__ out_rps) {
  __shared__ int sbuf[2][256][8];
  __shared__ int dropc;
  __shared__ float red[256];
  int tid = threadIdx.x;
  for (int i = tid; i < NEXP * CAP; i += 256) inv[i] = 0;   // zero (incl. padded tail)
  if (tid == 0) dropc = 0;
  int myr[32];
  int cnt[8] = {0,0,0,0,0,0,0,0};
  int tbase = tid * 32;
  for (int i = 0; i < 32; ++i) { int r = routes[tbase + i]; myr[i] = r; cnt[r]++; }
#pragma unroll
  for (int e = 0; e < 8; ++e) sbuf[0][tid][e] = cnt[e];
  __syncthreads();
  int cur = 0;
  for (int step = 1; step < 256; step <<= 1) {   // inclusive scan, 8 steps
#pragma unroll
    for (int e = 0; e < 8; ++e) {
      int v = sbuf[cur][tid][e];
      if (tid >= step) v += sbuf[cur][tid - step][e];
      sbuf[cur ^ 1][tid][e] = v;
    }
    __syncthreads();
    cur ^= 1;
  }
  int base[8];
#pragma unroll
  for (int e = 0; e < 8; ++e) base[e] = sbuf[cur][tid][e] - cnt[e];   // exclusive prefix
  for (int i = 0; i < 32; ++i) {
    int r = myr[i];
    int p = base[r]++;
    if (p < CAP) inv[r * CAP + p] = tbase + i;
    else         drop_list[atomicAdd(&dropc, 1)] = tbase + i;
  }
  if (tid < 8) {
    int c = min(sbuf[cur][255][tid], CAP);      // raw totals at last thread
    counts_i[tid] = c;
    out_counts[tid] = (float)c;
  }
  __syncthreads();
  if (tid == 0) {
    *ndrop_i = dropc;
    *out_ndrop = (float)dropc;
  }
  // deterministic route_prob_sums reduction
  {
    int e2 = tid & 7, j0 = tid >> 3;
    float s = 0.f;
    for (int j = j0; j < 2048; j += 32) s += partial[j * 8 + e2];
    red[tid] = s;
    __syncthreads();
    if (tid < 8) {
      float tt = 0.f;
      for (int k = 0; k < 32; ++k) tt += red[tid + 8 * k];
      out_rps[tid] = tt;
    }
  }
}

// ---------------- fill only dropped tokens: out[t] = x[t]*rpm[t] ----------------
__global__ void fill_dropped_kernel(const int* __restrict__ drop_list, const int* __restrict__ ndrop_i,
                                    const float* __restrict__ x, const float* __restrict__ rpm,
                                    float* __restrict__ outf) {
  int total = (*ndrop_i) * 256;    // float4s per dropped token row
  for (int i = blockIdx.x * blockDim.x + threadIdx.x; i < total; i += gridDim.x * blockDim.x) {
    int t = drop_list[i >> 8];
    int j = i & 255;
    float r = rpm[t];
    float4 v = ((const float4*)(x + (size_t)t * DDIM))[j];
    float4 o = {v.x * r, v.y * r, v.z * r, v.w * r};
    ((float4*)(outf + (size_t)t * DDIM))[j] = o;
  }
}

// ---------------- standalone transpose (only for nb<2 fallback) ----------------
__global__ void transpose_both_kernel(const float* __restrict__ W1, const float* __restrict__ W2,
                                      bf16_t* __restrict__ W1T, bf16_t* __restrict__ W2T,
                                      int nb, int e0) {
  __shared__ float tile[128][65];
  const int z = blockIdx.z;
  const int rem = blockIdx.x;          // 256 tiles per slice
  if (z < nb) {
    transpose_tile128(W1 + (size_t)(e0 + z) * ((size_t)DDIM * FDIM),
                      W1T + (size_t)z * ((size_t)DDIM * FDIM),
                      DDIM, FDIM, (rem & 31) * 128, (rem >> 5) * 128, tile, threadIdx.x);
  } else {
    transpose_tile128(W2 + (size_t)(e0 + z - nb) * ((size_t)FDIM * DDIM),
                      W2T + (size_t)(z - nb) * ((size_t)FDIM * DDIM),
                      FDIM, DDIM, (rem >> 5) * 128, (rem & 31) * 128, tile, threadIdx.x);
  }
}

// ============ MFMA GEMM: 128x128, BK=32, 4 waves, A-only LDS ring + B in registers ============
// R17 was LDS-BW bound: 48KB LDS traffic/tile-block vs 78cy MFMA (util 18.5% == ratio).
// Fix: B frags load DIRECTLY to VGPRs (4x dwordx4/lane/tile, MFMA-layout-exact,
// L2/L3-resident operand, 2x dup across wm-waves absorbed by L2). LDS carries only A:
// 24KB/tile-block -> ceiling ~2x.
// Per tile t (ledger-verified): loadB(t+1)->regs [4 gl] -> VMWAIT(6) [outstanding
// B(t) 4, A(t+1) 2, B(t+1) 4; keep 6 newest retires exactly B(t)+A(t)] -> s_barrier
// [publish A(t)] -> stageA(t+2) [slot (t-1)%3, dead post-barrier] -> 4 ds_read + 16
// MFMA. Last tile: VMWAIT(0). Unroll x2 with NAMED bE/bO reg buffers (no dyn index).
// Only loop vmem = 4 B-loads + 2 A-DMA (vmcnt counts depend on it; no spills at ~140 VGPR).
// A swizzle: granule s at row r holds K-granule s^((r>>1)&3); reads l4^((r>>1)&3).
// MODE 1 extra: blocks flat<ntiles run one W2T 128x128 chunk after, reusing smem (33KB).
template <int KDIM, int MODE, int TM>
__launch_bounds__(256, 3)
__global__ void gemm_kernel(const bf16_t* __restrict__ Abase, const bf16_t* __restrict__ Bbase,
                            const int* __restrict__ inv, const int* __restrict__ counts_i,
                            const float* __restrict__ bias_all, const float* __restrict__ rpm,
                            void* __restrict__ outp, int e0,
                            const float* __restrict__ Wsrc, bf16_t* __restrict__ Wdst,
                            int ntiles) {
  constexpr int MDIM = (MODE == 1) ? FDIM : DDIM;
  constexpr int NT = KDIM / 32;        // even for both instantiations
  constexpr int SLOT = 8192;           // A-only slot: 128 rows x 64B
  extern __shared__ __align__(16) char smem[];

  // T1: XCD-chunked bijective swizzle (nwg % 8 == 0 by construction)
  const int nx = gridDim.x, ny = gridDim.y;
  const int nwg = nx * ny * gridDim.z;
  const int flat = blockIdx.x + nx * (blockIdx.y + ny * blockIdx.z);
  const int nf = (flat & 7) * (nwg >> 3) + (flat >> 3);
  const int bx = nf % nx;
  const int tmp = nf / nx;
  const int by = tmp % ny, bz = tmp / ny;

  const int tid = threadIdx.x;
  const int e = e0 + bz;
  const int cnt = counts_i[e];
  const int c0 = bx * 128;
  const int m0 = by * TM;
  const bool doGemm = (c0 < cnt);      // uniform across block

  if (doGemm) {
    const bf16_t* A = Abase + (size_t)bz * ((size_t)MDIM * KDIM);
    const float* bias = bias_all + (size_t)e * MDIM;

    const int lane = tid & 63, w = tid >> 6;
    const int l15 = lane & 15, l4 = lane >> 4;
    const int wm = w >> 1, wn = w & 1;

    // ---- A stage sources (pre-swizzled global element offsets) ----
    size_t aOff[2];
#pragma unroll
    for (int u = 0; u < 2; ++u) {
      int r = u * 64 + (tid >> 2);
      int g = (tid & 3) ^ ((r >> 1) & 3);
      aOff[u] = (size_t)(m0 + r) * KDIM + g * 8;
    }
    // ---- B per-lane row pointers (MFMA-frag-exact direct loads) ----
    const bf16_t* bp[4];
#pragma unroll
    for (int nj = 0; nj < 4; ++nj) {
      int c = wn * 64 + nj * 16 + l15;
      if (MODE == 1) {
        int tok = inv[e * CAP + c0 + c];   // zeroed tail -> token 0 (result unread)
        bp[nj] = Bbase + (size_t)tok * KDIM + l4 * 8;
      } else {
        bp[nj] = Bbase + (size_t)bz * ((size_t)CAP * KDIM) + (size_t)(c0 + c) * KDIM + l4 * 8;
      }
    }

    // ---- swizzled A read offsets (within slot) ----
    int aRd[4];
#pragma unroll
    for (int mi = 0; mi < 4; ++mi) {
      int r = wm * 64 + mi * 16 + l15;
      aRd[mi] = r * 64 + ((l4 ^ ((r >> 1) & 3)) << 4);
    }

    auto stageA = [&](int t) {
      char* s = smem + (t % 3) * SLOT + w * 1024;
#pragma unroll
      for (int u = 0; u < 2; ++u) gload16(A + aOff[u] + t * 32, s + u * 4096);
    };

    f32x4 acc[4][4];
#pragma unroll
    for (int i = 0; i < 4; ++i)
#pragma unroll
      for (int j = 0; j < 4; ++j) acc[i][j] = (f32x4){0.f, 0.f, 0.f, 0.f};

    bf16x8 bE[4], bO[4];

#define LOADB(T, DST)                                                           \
    _Pragma("unroll") for (int nj = 0; nj < 4; ++nj)                            \
        DST[nj] = *(const bf16x8*)(bp[nj] + (T) * 32);

#define COMPUTE(T, BIN)                                                         \
    {                                                                           \
      const char* s_ = smem + ((T) % 3) * SLOT;                                 \
      bf16x8 af_[4];                                                            \
      _Pragma("unroll") for (int mi = 0; mi < 4; ++mi)                          \
          af_[mi] = *(const bf16x8*)(s_ + aRd[mi]);                             \
      __builtin_amdgcn_s_setprio(1);                                            \
      _Pragma("unroll") for (int mi = 0; mi < 4; ++mi)                          \
        _Pragma("unroll") for (int nj = 0; nj < 4; ++nj)                        \
          acc[mi][nj] = __builtin_amdgcn_mfma_f32_16x16x32_bf16(                \
              af_[mi], BIN[nj], acc[mi][nj], 0, 0, 0);                          \
      __builtin_amdgcn_s_setprio(0);                                            \
    }

    // prologue: B(0) then A(0), A(1)  -> outstanding [B0 4, A0 2, A1 2]
    LOADB(0, bE);
    stageA(0); stageA(1);

    for (int tt = 0; tt < NT; tt += 2) {
      {  // even tile t = tt (uses bE); loads B(t+1) into bO
        const int t = tt;
        LOADB(t + 1, bO);
        VMWAIT(6);                     // retires B(t)+A(t); keeps A(t+1), B(t+1)
        BARR;                          // publish A(t)
        if (t + 2 < NT) stageA(t + 2); // slot (t-1)%3: dead post-barrier
        COMPUTE(t, bE);
      }
      {  // odd tile t = tt+1 (uses bO); loads B(t+1) into bE
        const int t = tt + 1;
        if (t + 1 < NT) {
          LOADB(t + 1, bE);
          VMWAIT(6);
        } else {
          VMWAIT(0);                   // last tile: drain
        }
        BARR;
        if (t + 2 < NT) stageA(t + 2);
        COMPUTE(t, bO);
      }
    }
#undef LOADB
#undef COMPUTE

    // ---- epilogue: D layout col=lane&15, row=(lane>>4)*4+reg [verified m89/m91] ----
    if constexpr (MODE == 1) {
      bf16_t* h = (bf16_t*)outp + (size_t)bz * ((size_t)CAP * FDIM);
#pragma unroll
      for (int nj = 0; nj < 4; ++nj) {
        int c = c0 + wn * 64 + nj * 16 + l15;
        bf16_t* hrow = h + (size_t)c * FDIM;
#pragma unroll
        for (int mi = 0; mi < 4; ++mi) {
          int f = m0 + wm * 64 + mi * 16 + l4 * 4;
          const float4 bi = *(const float4*)&bias[f];
          f32x4 v = acc[mi][nj];
          bf16x4 hv;
          hv[0] = (bf16_t)fmaxf(v[0] + bi.x, 0.f);
          hv[1] = (bf16_t)fmaxf(v[1] + bi.y, 0.f);
          hv[2] = (bf16_t)fmaxf(v[2] + bi.z, 0.f);
          hv[3] = (bf16_t)fmaxf(v[3] + bi.w, 0.f);
          *(bf16x4*)&hrow[f] = hv;
        }
      }
    } else {
      float* finalp = (float*)outp;
#pragma unroll
      for (int nj = 0; nj < 4; ++nj) {
        int c = c0 + wn * 64 + nj * 16 + l15;
        if (c < cnt) {
          int tok = inv[e * CAP + c];
          float r = rpm[tok];
          float* orow = finalp + (size_t)tok * DDIM;
#pragma unroll
          for (int mi = 0; mi < 4; ++mi) {
            int dd = m0 + wm * 64 + mi * 16 + l4 * 4;
            const float4 bi = *(const float4*)&bias[dd];
            f32x4 v = acc[mi][nj];
            float4 o;
            o.x = (v[0] + bi.x) * r;
            o.y = (v[1] + bi.y) * r;
            o.z = (v[2] + bi.z) * r;
            o.w = (v[3] + bi.w) * r;
            *(float4*)&orow[dd] = o;
          }
        }
      }
    }
  }

  // ---- interleaved W2T chunk (MODE 1 only): reuse smem as f32[128][65] ----
  if constexpr (MODE == 1) {
    if (Wsrc != nullptr && flat < ntiles) {
      if (doGemm) BARR;                 // all waves' ring ds_reads retired
      const int z2 = flat >> 8;
      const int rem = flat & 255;
      transpose_tile128(Wsrc + (size_t)z2 * ((size_t)FDIM * DDIM),
                        Wdst + (size_t)z2 * ((size_t)FDIM * DDIM),
                        FDIM, DDIM, (rem >> 5) * 128, (rem & 31) * 128,
                        (float(*)[65])smem, tid);
    }
  }
}

// ---------------- host launcher ----------------
extern "C" void kernel_launch(void* const* d_in, const int* in_sizes, int n_in,
                              void* d_out, int out_size, void* d_ws, size_t ws_size,
                              hipStream_t stream) {
  (void)in_sizes; (void)n_in; (void)out_size;
  const float* x   = (const float*)d_in[0];
  const float* wsw = (const float*)d_in[1];
  const float* bsw = (const float*)d_in[2];
  const float* W1  = (const float*)d_in[3];
  const float* b1  = (const float*)d_in[4];
  const float* W2  = (const float*)d_in[5];
  const float* b2  = (const float*)d_in[6];

  float* out_final  = (float*)d_out;            // [T][D]
  float* out_counts = out_final + 8388608;      // [8]
  float* out_rps    = out_final + 8388616;      // [8]
  float* out_ndrop  = out_final + 8388624;      // [1]
  float* out_rpm    = out_final + 8388625;      // [T] (output 5 of reference)

  char* ws = (char*)d_ws;
  size_t off = 0;
  auto carve = [&](size_t bytes) {
    char* p = ws + off;
    off += (bytes + 255) & ~(size_t)255;
    return p;
  };
  bf16_t* xbf      = (bf16_t*)carve((size_t)T_TOK * DDIM * 2);   // 16 MB
  int*    routes   = (int*)   carve((size_t)T_TOK * 4);
  int*    inv      = (int*)   carve((size_t)NEXP * CAP * 4);
  int*    counts_i = (int*)   carve((size_t)NEXP * 4);
  float*  partial  = (float*) carve((size_t)2048 * 8 * 4);
  int*    drop_list= (int*)   carve((size_t)T_TOK * 4);
  int*    ndrop_i  = (int*)   carve(256);
  size_t fixed = off;
  const size_t PER_E = 2 * (size_t)FDIM * DDIM * 2 + (size_t)CAP * FDIM * 2; // 32MB
  int nb = 8;
  while (nb > 1 && fixed + (size_t)nb * PER_E > ws_size) nb >>= 1;
  bf16_t* W1T  = (bf16_t*)carve((size_t)nb * FDIM * DDIM * 2);
  bf16_t* W2T  = (bf16_t*)carve((size_t)nb * DDIM * FDIM * 2);
  bf16_t* hbuf = (bf16_t*)carve((size_t)nb * CAP * FDIM * 2);

  const bool fuse = (nb >= 2);
  const int nrouter = T_TOK / 4;
  const int ntransK1 = fuse ? nb * 256 : 0;   // W1T tiles for first batch
  const int SMEM_G1 = 33280;                  // max(3*8192 ring, 128*65*4 transpose)
  const int SMEM_G2 = 3 * 8192;               // A-only ring

  router_w1t_kernel<<<nrouter + ntransK1, 256, 0, stream>>>(
      x, wsw, bsw, routes, out_rpm, partial, xbf, W1, W1T, nrouter);
  scan_kernel<<<1, 256, 0, stream>>>(routes, inv, counts_i, out_counts, out_ndrop,
                                     drop_list, ndrop_i, partial, out_rps);
  fill_dropped_kernel<<<256, 256, 0, stream>>>(drop_list, ndrop_i, x, out_rpm, out_final);

  for (int e0 = 0; e0 < NEXP; e0 += nb) {
    if (e0 == 0 && fuse) {
      // GEMM1 with W2T chunks interleaved into the first nb*256 blocks
      gemm_kernel<DDIM, 1, 128><<<dim3(CAP / 128, FDIM / 128, nb), 256, SMEM_G1, stream>>>(
          W1T, xbf, inv, counts_i, b1, nullptr, hbuf, e0, W2, W2T, nb * 256);
    } else {
      transpose_both_kernel<<<dim3(256, 1, 2 * nb), 256, 0, stream>>>(W1, W2, W1T, W2T, nb, e0);
      gemm_kernel<DDIM, 1, 128><<<dim3(CAP / 128, FDIM / 128, nb), 256, SMEM_G1, stream>>>(
          W1T, xbf, inv, counts_i, b1, nullptr, hbuf, e0, nullptr, nullptr, 0);
    }
    gemm_kernel<FDIM, 2, 128><<<dim3(CAP / 128, DDIM / 128, nb), 256, SMEM_G2, stream>>>(
        W2T, hbuf, inv, counts_i, b2, out_rpm, d_out, e0, nullptr, nullptr, 0);
  }
}

// Round 19
// 367.226 us; speedup vs baseline: 1.5384x; 1.5384x over previous
//
#include <hip/hip_runtime.h>
#include <hip/hip_bf16.h>
#include <cstdint>
#include <cstddef>

// Problem constants (fixed by reference)
#define T_TOK 8192
#define DDIM  1024
#define FDIM  4096
#define NEXP  8
#define CAP   2048   // int(2.0 * T / E)

typedef __bf16 bf16_t;
typedef __bf16 bf16x8 __attribute__((ext_vector_type(8)));
typedef __bf16 bf16x4 __attribute__((ext_vector_type(4)));
typedef float  f32x4  __attribute__((ext_vector_type(4)));

// async global->LDS: lds dest must be WAVE-UNIFORM base; HW adds lane*16
__device__ __forceinline__ void gload16(const void* g, void* l) {
  __builtin_amdgcn_global_load_lds(
      (const __attribute__((address_space(1))) unsigned int*)g,
      (__attribute__((address_space(3))) unsigned int*)l,
      16, 0, 0);
}

#define VMWAIT(N) asm volatile("s_waitcnt vmcnt(" #N ")" ::: "memory")
#define BARR asm volatile("s_barrier" ::: "memory")

// ---- shared 128x128 transpose+convert tile body (PIPELINED halves) ----
// S[R][C] f32 -> D[C][R] bf16. All 16 float4 loads issued before the first LDS
// write. LDS swizzle: phys_col(r,c) = c ^ ((r>>5)<<2) -> phase2 read 2-way (free).
__device__ __forceinline__ void transpose_tile128(const float* __restrict__ s, bf16_t* __restrict__ d,
                                                  int R, int C, int bx, int by,
                                                  float (*tile)[65], int tid) {
  const int r0 = tid >> 4;
  const int c4 = (tid & 15) * 4;
  const int cq = tid >> 4;
  const int dk = (tid & 15) * 8;
  float4 v0[8], v1[8];
#pragma unroll
  for (int p = 0; p < 8; ++p)
    v0[p] = *(const float4*)&s[(size_t)(by + r0 + p * 16) * C + bx + c4];
#pragma unroll
  for (int p = 0; p < 8; ++p)          // half-2 loads issued early (held in regs)
    v1[p] = *(const float4*)&s[(size_t)(by + r0 + p * 16) * C + bx + 64 + c4];

  auto wr_lds = [&](float4* v) {
#pragma unroll
    for (int p = 0; p < 8; ++p) {
      int r = r0 + p * 16;
      int sw = (r >> 5) << 2;
      tile[r][(c4 + 0) ^ sw] = v[p].x; tile[r][(c4 + 1) ^ sw] = v[p].y;
      tile[r][(c4 + 2) ^ sw] = v[p].z; tile[r][(c4 + 3) ^ sw] = v[p].w;
    }
  };
  auto phase2 = [&](int ch0) {
#pragma unroll
    for (int q = 0; q < 4; ++q) {
      int c = cq + 16 * q;
      bf16x8 o;
#pragma unroll
      for (int j = 0; j < 8; ++j) {
        int r = dk + j;
        o[j] = (bf16_t)tile[r][c ^ ((r >> 5) << 2)];
      }
      *(bf16x8*)&d[(size_t)(ch0 + c) * R + by + dk] = o;
    }
  };

  wr_lds(v0);
  __syncthreads();
  phase2(bx);
  __syncthreads();
  wr_lds(v1);
  __syncthreads();
  phase2(bx + 64);
}

// ======== K1: router (blocks [0,nrouter)) + W1T transpose (rest) ========
__global__ void router_w1t_kernel(const float* __restrict__ x, const float* __restrict__ wsw,
                                  const float* __restrict__ bsw, int* __restrict__ routes,
                                  float* __restrict__ rpm, float* __restrict__ partial,
                                  bf16_t* __restrict__ xbf,
                                  const float* __restrict__ W1, bf16_t* __restrict__ W1T,
                                  int nrouter) {
  __shared__ float tile[128][65];
  const int bid = blockIdx.x;
  const int tid = threadIdx.x;
  if (bid >= nrouter) {
    const int tbid = bid - nrouter;
    const int z = tbid >> 8;
    const int rem = tbid & 255;
    transpose_tile128(W1 + (size_t)z * ((size_t)DDIM * FDIM),
                      W1T + (size_t)z * ((size_t)DDIM * FDIM),
                      DDIM, FDIM, (rem & 31) * 128, (rem >> 5) * 128, tile, tid);
  } else {
    const int rb = bid;
    const int wv = tid >> 6, lane = tid & 63;
    const int t = rb * 4 + wv;
    const float4* xr = (const float4*)(x + (size_t)t * DDIM);
    float4 xv[4];
    float a[8] = {0.f,0.f,0.f,0.f,0.f,0.f,0.f,0.f};
#pragma unroll
    for (int p = 0; p < 4; ++p) {
      xv[p] = xr[lane + p * 64];
#pragma unroll
      for (int j = 0; j < 4; ++j) {
        float v = ((const float*)&xv[p])[j];
        int d2 = (lane + p * 64) * 4 + j;
        const float4* wr = (const float4*)(wsw + d2 * 8);
        float4 w0 = wr[0], w1 = wr[1];
        a[0] += v * w0.x; a[1] += v * w0.y; a[2] += v * w0.z; a[3] += v * w0.w;
        a[4] += v * w1.x; a[5] += v * w1.y; a[6] += v * w1.z; a[7] += v * w1.w;
      }
    }
#pragma unroll
    for (int e = 0; e < 8; ++e) {
#pragma unroll
      for (int off = 32; off > 0; off >>= 1) a[e] += __shfl_xor(a[e], off);
      a[e] += bsw[e];
    }
    float m = a[0]; int arg = 0;
#pragma unroll
    for (int e = 1; e < 8; ++e) { if (a[e] > m) { m = a[e]; arg = e; } }
    float p8[8]; float s2 = 0.f;
#pragma unroll
    for (int e = 0; e < 8; ++e) { p8[e] = expf(a[e] - m); s2 += p8[e]; }
    float inv_s = 1.f / s2;   // = softmax max since p[arg]=1
    bf16_t* xbr = xbf + (size_t)t * DDIM;
#pragma unroll
    for (int p = 0; p < 4; ++p) {
      int i4 = lane + p * 64;
      bf16x4 hb;
      hb[0] = (bf16_t)xv[p].x; hb[1] = (bf16_t)xv[p].y;
      hb[2] = (bf16_t)xv[p].z; hb[3] = (bf16_t)xv[p].w;
      *(bf16x4*)(xbr + (size_t)i4 * 4) = hb;
    }
    float* pp = &tile[0][0];             // reuse LDS: [4][8]
    if (lane == 0) {
      routes[t] = arg;
      rpm[t] = inv_s;
#pragma unroll
      for (int e = 0; e < 8; ++e) pp[wv * 8 + e] = p8[e] * inv_s;
    }
    __syncthreads();
    if (tid < 8) {
      int e = tid;
      partial[(size_t)rb * 8 + e] = pp[0 + e] + pp[8 + e] + pp[16 + e] + pp[24 + e];
    }
  }
}

// ---- scan: PARALLEL prefix (Hillis-Steele over 256 thr x 8 experts) + dispatch + rps ----
__global__ void scan_kernel(const int* __restrict__ routes, int* __restrict__ inv,
                            int* __restrict__ counts_i, float* __restrict__ out_counts,
                            float* __restrict__ out_ndrop, int* __restrict__ drop_list,
                            int* __restrict__ ndrop_i, const float* __restrict__ partial,
                            float* __restrict__ out_rps) {
  __shared__ int sbuf[2][256][8];
  __shared__ int dropc;
  __shared__ float red[256];
  int tid = threadIdx.x;
  for (int i = tid; i < NEXP * CAP; i += 256) inv[i] = 0;   // zero (incl. padded tail)
  if (tid == 0) dropc = 0;
  int myr[32];
  int cnt[8] = {0,0,0,0,0,0,0,0};
  int tbase = tid * 32;
  for (int i = 0; i < 32; ++i) { int r = routes[tbase + i]; myr[i] = r; cnt[r]++; }
#pragma unroll
  for (int e = 0; e < 8; ++e) sbuf[0][tid][e] = cnt[e];
  __syncthreads();
  int cur = 0;
  for (int step = 1; step < 256; step <<= 1) {   // inclusive scan, 8 steps
#pragma unroll
    for (int e = 0; e < 8; ++e) {
      int v = sbuf[cur][tid][e];
      if (tid >= step) v += sbuf[cur][tid - step][e];
      sbuf[cur ^ 1][tid][e] = v;
    }
    __syncthreads();
    cur ^= 1;
  }
  int base[8];
#pragma unroll
  for (int e = 0; e < 8; ++e) base[e] = sbuf[cur][tid][e] - cnt[e];   // exclusive prefix
  for (int i = 0; i < 32; ++i) {
    int r = myr[i];
    int p = base[r]++;
    if (p < CAP) inv[r * CAP + p] = tbase + i;
    else         drop_list[atomicAdd(&dropc, 1)] = tbase + i;
  }
  if (tid < 8) {
    int c = min(sbuf[cur][255][tid], CAP);      // raw totals at last thread
    counts_i[tid] = c;
    out_counts[tid] = (float)c;
  }
  __syncthreads();
  if (tid == 0) {
    *ndrop_i = dropc;
    *out_ndrop = (float)dropc;
  }
  // deterministic route_prob_sums reduction
  {
    int e2 = tid & 7, j0 = tid >> 3;
    float s = 0.f;
    for (int j = j0; j < 2048; j += 32) s += partial[j * 8 + e2];
    red[tid] = s;
    __syncthreads();
    if (tid < 8) {
      float tt = 0.f;
      for (int k = 0; k < 32; ++k) tt += red[tid + 8 * k];
      out_rps[tid] = tt;
    }
  }
}

// ---------------- fill only dropped tokens: out[t] = x[t]*rpm[t] ----------------
__global__ void fill_dropped_kernel(const int* __restrict__ drop_list, const int* __restrict__ ndrop_i,
                                    const float* __restrict__ x, const float* __restrict__ rpm,
                                    float* __restrict__ outf) {
  int total = (*ndrop_i) * 256;    // float4s per dropped token row
  for (int i = blockIdx.x * blockDim.x + threadIdx.x; i < total; i += gridDim.x * blockDim.x) {
    int t = drop_list[i >> 8];
    int j = i & 255;
    float r = rpm[t];
    float4 v = ((const float4*)(x + (size_t)t * DDIM))[j];
    float4 o = {v.x * r, v.y * r, v.z * r, v.w * r};
    ((float4*)(outf + (size_t)t * DDIM))[j] = o;
  }
}

// ---------------- standalone transpose (only for nb<2 fallback) ----------------
__global__ void transpose_both_kernel(const float* __restrict__ W1, const float* __restrict__ W2,
                                      bf16_t* __restrict__ W1T, bf16_t* __restrict__ W2T,
                                      int nb, int e0) {
  __shared__ float tile[128][65];
  const int z = blockIdx.z;
  const int rem = blockIdx.x;          // 256 tiles per slice
  if (z < nb) {
    transpose_tile128(W1 + (size_t)(e0 + z) * ((size_t)DDIM * FDIM),
                      W1T + (size_t)z * ((size_t)DDIM * FDIM),
                      DDIM, FDIM, (rem & 31) * 128, (rem >> 5) * 128, tile, threadIdx.x);
  } else {
    transpose_tile128(W2 + (size_t)(e0 + z - nb) * ((size_t)FDIM * DDIM),
                      W2T + (size_t)(z - nb) * ((size_t)FDIM * DDIM),
                      FDIM, DDIM, (rem >> 5) * 128, (rem & 31) * 128, tile, threadIdx.x);
  }
}

// ====== MFMA GEMM: 128x128, BK=32, 4 waves, (DEPTH+1)-slot LDS ring, depth-DEPTH prefetch ======
// R17-verified structure (363.5us total). Per tile t: VMWAIT retires exactly stage(t)
// [outstanding = stages t..min(t+DEPTH-1,NT-1), 4 gloads each] -> s_barrier [publish
// A+B of t; joins compute(t-1)] -> stage(t+DEPTH) [slot (t+DEPTH)%(DEPTH+1) ==
// (t-1)%(DEPTH+1): all waves' reads done before this barrier] -> 8 ds_read + 16 MFMA.
// Swizzle: granule s at row r holds K-granule s^((r>>1)&3); reads l4^((r>>1)&3).
// DEPTH=2: 48KB ring, 3 blocks/CU (R17 exact). DEPTH=3: 64KB ring, 2 blocks/CU,
// issue->wait distance 3 tile bodies (~1300cy > HBM 900) — GEMM2 experiment.
// MODE 1 extra: blocks flat<ntiles run one W2T 128x128 chunk after, reusing smem (33KB).
template <int KDIM, int MODE, int TM, int DEPTH>
__launch_bounds__(256, 3)
__global__ void gemm_kernel(const bf16_t* __restrict__ Abase, const bf16_t* __restrict__ Bbase,
                            const int* __restrict__ inv, const int* __restrict__ counts_i,
                            const float* __restrict__ bias_all, const float* __restrict__ rpm,
                            void* __restrict__ outp, int e0,
                            const float* __restrict__ Wsrc, bf16_t* __restrict__ Wdst,
                            int ntiles) {
  static_assert(TM == 128, "ring constants assume TM=128");
  constexpr int MDIM = (MODE == 1) ? FDIM : DDIM;
  constexpr int NT = KDIM / 32;
  constexpr int NSLOT = DEPTH + 1;
  constexpr int ABYTES = 8192;         // A region per slot (128 rows x 64B)
  constexpr int SLOT = ABYTES + 8192;  // + B region
  extern __shared__ __align__(16) char smem[];

  // T1: XCD-chunked bijective swizzle (nwg % 8 == 0 by construction)
  const int nx = gridDim.x, ny = gridDim.y;
  const int nwg = nx * ny * gridDim.z;
  const int flat = blockIdx.x + nx * (blockIdx.y + ny * blockIdx.z);
  const int nf = (flat & 7) * (nwg >> 3) + (flat >> 3);
  const int bx = nf % nx;
  const int tmp = nf / nx;
  const int by = tmp % ny, bz = tmp / ny;

  const int tid = threadIdx.x;
  const int e = e0 + bz;
  const int cnt = counts_i[e];
  const int c0 = bx * 128;
  const int m0 = by * TM;
  const bool doGemm = (c0 < cnt);      // uniform across block

  if (doGemm) {
    const bf16_t* A = Abase + (size_t)bz * ((size_t)MDIM * KDIM);
    const float* bias = bias_all + (size_t)e * MDIM;

    const int lane = tid & 63, w = tid >> 6;
    const int l15 = lane & 15, l4 = lane >> 4;
    const int wm = w >> 1, wn = w & 1;

    // ---- stage sources (pre-swizzled global element offsets / pointers) ----
    size_t aOff[2];
#pragma unroll
    for (int u = 0; u < 2; ++u) {
      int r = u * 64 + (tid >> 2);
      int g = (tid & 3) ^ ((r >> 1) & 3);
      aOff[u] = (size_t)(m0 + r) * KDIM + g * 8;
    }
    const bf16_t* bPtr[2];
#pragma unroll
    for (int v = 0; v < 2; ++v) {
      int c = v * 64 + (tid >> 2);
      int g = (tid & 3) ^ ((c >> 1) & 3);
      if (MODE == 1) {
        int tok = inv[e * CAP + c0 + c];   // zeroed tail -> token 0 (result unread)
        bPtr[v] = Bbase + (size_t)tok * KDIM + g * 8;
      } else {
        bPtr[v] = Bbase + (size_t)bz * ((size_t)CAP * KDIM) + (size_t)(c0 + c) * KDIM + g * 8;
      }
    }

    // ---- swizzled read offsets (within slot; A at 0, B at +ABYTES) ----
    int aRd[4], bRd[4];
#pragma unroll
    for (int mi = 0; mi < 4; ++mi) {
      int r = wm * 64 + mi * 16 + l15;
      aRd[mi] = r * 64 + ((l4 ^ ((r >> 1) & 3)) << 4);
    }
#pragma unroll
    for (int nj = 0; nj < 4; ++nj) {
      int c = wn * 64 + nj * 16 + l15;
      bRd[nj] = ABYTES + c * 64 + ((l4 ^ ((c >> 1) & 3)) << 4);
    }

    auto stage = [&](int t) {
      char* s = smem + (t % NSLOT) * SLOT + w * 1024;
#pragma unroll
      for (int u = 0; u < 2; ++u) gload16(A + aOff[u] + t * 32, s + u * 4096);
#pragma unroll
      for (int v = 0; v < 2; ++v) gload16(bPtr[v] + t * 32, s + ABYTES + v * 4096);
    };

    f32x4 acc[4][4];
#pragma unroll
    for (int i = 0; i < 4; ++i)
#pragma unroll
      for (int j = 0; j < 4; ++j) acc[i][j] = (f32x4){0.f, 0.f, 0.f, 0.f};

    // prologue: DEPTH tiles in flight
#pragma unroll
    for (int d = 0; d < DEPTH; ++d) stage(d);

    for (int t = 0; t < NT; ++t) {
      const int rem = NT - t;            // tiles left incl. t
      if constexpr (DEPTH == 2) {
        if (rem >= 2) { VMWAIT(4); } else { VMWAIT(0); }
      } else {
        if (rem >= 3) { VMWAIT(8); } else if (rem == 2) { VMWAIT(4); } else { VMWAIT(0); }
      }
      BARR;                              // publish tile t to all waves
      if (t + DEPTH < NT) stage(t + DEPTH);   // slot (t-1)%NSLOT: dead post-barrier
      const char* s = smem + (t % NSLOT) * SLOT;
      bf16x8 af[4], bf[4];
#pragma unroll
      for (int mi = 0; mi < 4; ++mi) af[mi] = *(const bf16x8*)(s + aRd[mi]);
#pragma unroll
      for (int nj = 0; nj < 4; ++nj) bf[nj] = *(const bf16x8*)(s + bRd[nj]);
      __builtin_amdgcn_s_setprio(1);
#pragma unroll
      for (int mi = 0; mi < 4; ++mi)
#pragma unroll
        for (int nj = 0; nj < 4; ++nj)
          acc[mi][nj] = __builtin_amdgcn_mfma_f32_16x16x32_bf16(af[mi], bf[nj], acc[mi][nj], 0, 0, 0);
      __builtin_amdgcn_s_setprio(0);
    }

    // ---- epilogue: D layout col=lane&15, row=(lane>>4)*4+reg [verified m89/m91] ----
    if constexpr (MODE == 1) {
      bf16_t* h = (bf16_t*)outp + (size_t)bz * ((size_t)CAP * FDIM);
#pragma unroll
      for (int nj = 0; nj < 4; ++nj) {
        int c = c0 + wn * 64 + nj * 16 + l15;
        bf16_t* hrow = h + (size_t)c * FDIM;
#pragma unroll
        for (int mi = 0; mi < 4; ++mi) {
          int f = m0 + wm * 64 + mi * 16 + l4 * 4;
          const float4 bi = *(const float4*)&bias[f];
          f32x4 v = acc[mi][nj];
          bf16x4 hv;
          hv[0] = (bf16_t)fmaxf(v[0] + bi.x, 0.f);
          hv[1] = (bf16_t)fmaxf(v[1] + bi.y, 0.f);
          hv[2] = (bf16_t)fmaxf(v[2] + bi.z, 0.f);
          hv[3] = (bf16_t)fmaxf(v[3] + bi.w, 0.f);
          *(bf16x4*)&hrow[f] = hv;
        }
      }
    } else {
      float* finalp = (float*)outp;
#pragma unroll
      for (int nj = 0; nj < 4; ++nj) {
        int c = c0 + wn * 64 + nj * 16 + l15;
        if (c < cnt) {
          int tok = inv[e * CAP + c];
          float r = rpm[tok];
          float* orow = finalp + (size_t)tok * DDIM;
#pragma unroll
          for (int mi = 0; mi < 4; ++mi) {
            int dd = m0 + wm * 64 + mi * 16 + l4 * 4;
            const float4 bi = *(const float4*)&bias[dd];
            f32x4 v = acc[mi][nj];
            float4 o;
            o.x = (v[0] + bi.x) * r;
            o.y = (v[1] + bi.y) * r;
            o.z = (v[2] + bi.z) * r;
            o.w = (v[3] + bi.w) * r;
            *(float4*)&orow[dd] = o;
          }
        }
      }
    }
  }

  // ---- interleaved W2T chunk (MODE 1 only): reuse smem as f32[128][65] ----
  if constexpr (MODE == 1) {
    if (Wsrc != nullptr && flat < ntiles) {
      if (doGemm) BARR;                 // all waves' ring ds_reads retired
      const int z2 = flat >> 8;
      const int rem = flat & 255;
      transpose_tile128(Wsrc + (size_t)z2 * ((size_t)FDIM * DDIM),
                        Wdst + (size_t)z2 * ((size_t)FDIM * DDIM),
                        FDIM, DDIM, (rem >> 5) * 128, (rem & 31) * 128,
                        (float(*)[65])smem, tid);
    }
  }
}

// ---------------- host launcher ----------------
extern "C" void kernel_launch(void* const* d_in, const int* in_sizes, int n_in,
                              void* d_out, int out_size, void* d_ws, size_t ws_size,
                              hipStream_t stream) {
  (void)in_sizes; (void)n_in; (void)out_size;
  const float* x   = (const float*)d_in[0];
  const float* wsw = (const float*)d_in[1];
  const float* bsw = (const float*)d_in[2];
  const float* W1  = (const float*)d_in[3];
  const float* b1  = (const float*)d_in[4];
  const float* W2  = (const float*)d_in[5];
  const float* b2  = (const float*)d_in[6];

  float* out_final  = (float*)d_out;            // [T][D]
  float* out_counts = out_final + 8388608;      // [8]
  float* out_rps    = out_final + 8388616;      // [8]
  float* out_ndrop  = out_final + 8388624;      // [1]
  float* out_rpm    = out_final + 8388625;      // [T] (output 5 of reference)

  char* ws = (char*)d_ws;
  size_t off = 0;
  auto carve = [&](size_t bytes) {
    char* p = ws + off;
    off += (bytes + 255) & ~(size_t)255;
    return p;
  };
  bf16_t* xbf      = (bf16_t*)carve((size_t)T_TOK * DDIM * 2);   // 16 MB
  int*    routes   = (int*)   carve((size_t)T_TOK * 4);
  int*    inv      = (int*)   carve((size_t)NEXP * CAP * 4);
  int*    counts_i = (int*)   carve((size_t)NEXP * 4);
  float*  partial  = (float*) carve((size_t)2048 * 8 * 4);
  int*    drop_list= (int*)   carve((size_t)T_TOK * 4);
  int*    ndrop_i  = (int*)   carve(256);
  size_t fixed = off;
  const size_t PER_E = 2 * (size_t)FDIM * DDIM * 2 + (size_t)CAP * FDIM * 2; // 32MB
  int nb = 8;
  while (nb > 1 && fixed + (size_t)nb * PER_E > ws_size) nb >>= 1;
  bf16_t* W1T  = (bf16_t*)carve((size_t)nb * FDIM * DDIM * 2);
  bf16_t* W2T  = (bf16_t*)carve((size_t)nb * DDIM * FDIM * 2);
  bf16_t* hbuf = (bf16_t*)carve((size_t)nb * CAP * FDIM * 2);

  const bool fuse = (nb >= 2);
  const int nrouter = T_TOK / 4;
  const int ntransK1 = fuse ? nb * 256 : 0;   // W1T tiles for first batch
  const int SMEM_G1 = 49152;                  // 3-slot ring (>= 33280 transpose tile)
  const int SMEM_G2 = 65536;                  // 4-slot ring (depth-3)

  // 64KB dynamic LDS opt-in for GEMM2 (runtime attr; graph-capture safe)
  hipFuncSetAttribute((const void*)gemm_kernel<FDIM, 2, 128, 3>,
                      hipFuncAttributeMaxDynamicSharedMemorySize, SMEM_G2);

  router_w1t_kernel<<<nrouter + ntransK1, 256, 0, stream>>>(
      x, wsw, bsw, routes, out_rpm, partial, xbf, W1, W1T, nrouter);
  scan_kernel<<<1, 256, 0, stream>>>(routes, inv, counts_i, out_counts, out_ndrop,
                                     drop_list, ndrop_i, partial, out_rps);
  fill_dropped_kernel<<<256, 256, 0, stream>>>(drop_list, ndrop_i, x, out_rpm, out_final);

  for (int e0 = 0; e0 < NEXP; e0 += nb) {
    if (e0 == 0 && fuse) {
      // GEMM1 (depth-2, R17 exact) with W2T chunks interleaved into first nb*256 blocks
      gemm_kernel<DDIM, 1, 128, 2><<<dim3(CAP / 128, FDIM / 128, nb), 256, SMEM_G1, stream>>>(
          W1T, xbf, inv, counts_i, b1, nullptr, hbuf, e0, W2, W2T, nb * 256);
    } else {
      transpose_both_kernel<<<dim3(256, 1, 2 * nb), 256, 0, stream>>>(W1, W2, W1T, W2T, nb, e0);
      gemm_kernel<DDIM, 1, 128, 2><<<dim3(CAP / 128, FDIM / 128, nb), 256, SMEM_G1, stream>>>(
          W1T, xbf, inv, counts_i, b1, nullptr, hbuf, e0, nullptr, nullptr, 0);
    }
    // GEMM2: depth-3 / 4-slot experiment (GEMM1 above is the in-bench control)
    gemm_kernel<FDIM, 2, 128, 3><<<dim3(CAP / 128, DDIM / 128, nb), 256, SMEM_G2, stream>>>(
        W2T, hbuf, inv, counts_i, b2, out_rpm, d_out, e0, nullptr, nullptr, 0);
  }
}

// Round 20
// 361.189 us; speedup vs baseline: 1.5641x; 1.0167x over previous
//
#include <hip/hip_runtime.h>
#include <hip/hip_bf16.h>
#include <hip/hip_fp8.h>
#include <cstdint>
#include <cstddef>

// Problem constants (fixed by reference)
#define T_TOK 8192
#define DDIM  1024
#define FDIM  4096
#define NEXP  8
#define CAP   2048   // int(2.0 * T / E)

typedef unsigned char fp8_t;          // OCP e4m3 storage
typedef __bf16 bf16_t;
typedef float  f32x4  __attribute__((ext_vector_type(4)));

#define WSCALE 64.0f                  // weights scaled into e4m3 normal range
#define INV_WSCALE 0.015625f

// async global->LDS: lds dest must be WAVE-UNIFORM base; HW adds lane*16
__device__ __forceinline__ void gload16(const void* g, void* l) {
  __builtin_amdgcn_global_load_lds(
      (const __attribute__((address_space(1))) unsigned int*)g,
      (__attribute__((address_space(3))) unsigned int*)l,
      16, 0, 0);
}

#define VMWAIT(N) asm volatile("s_waitcnt vmcnt(" #N ")" ::: "memory")
#define BARR asm volatile("s_barrier" ::: "memory")

__device__ __forceinline__ unsigned char f8e4m3(float v) {
  __hip_fp8_e4m3 q(v);
  return *reinterpret_cast<unsigned char*>(&q);
}
__device__ __forceinline__ unsigned f8pack4(float a, float b, float c, float d) {
  return (unsigned)f8e4m3(a) | ((unsigned)f8e4m3(b) << 8)
       | ((unsigned)f8e4m3(c) << 16) | ((unsigned)f8e4m3(d) << 24);
}

// ---- shared 128x128 transpose+convert tile body (f32 -> fp8 e4m3, scaled) ----
// S[R][C] f32 -> D[C][R] fp8 (value * scale). All 16 float4 loads issued before
// first LDS write. LDS swizzle: phys_col(r,c)=c^((r>>5)<<2) -> phase2 read 2-way.
__device__ __forceinline__ void transpose_tile128(const float* __restrict__ s, fp8_t* __restrict__ d,
                                                  int R, int C, int bx, int by,
                                                  float (*tile)[65], int tid, float scale) {
  const int r0 = tid >> 4;
  const int c4 = (tid & 15) * 4;
  const int cq = tid >> 4;
  const int dk = (tid & 15) * 8;
  float4 v0[8], v1[8];
#pragma unroll
  for (int p = 0; p < 8; ++p)
    v0[p] = *(const float4*)&s[(size_t)(by + r0 + p * 16) * C + bx + c4];
#pragma unroll
  for (int p = 0; p < 8; ++p)          // half-2 loads issued early (held in regs)
    v1[p] = *(const float4*)&s[(size_t)(by + r0 + p * 16) * C + bx + 64 + c4];

  auto wr_lds = [&](float4* v) {
#pragma unroll
    for (int p = 0; p < 8; ++p) {
      int r = r0 + p * 16;
      int sw = (r >> 5) << 2;
      tile[r][(c4 + 0) ^ sw] = v[p].x; tile[r][(c4 + 1) ^ sw] = v[p].y;
      tile[r][(c4 + 2) ^ sw] = v[p].z; tile[r][(c4 + 3) ^ sw] = v[p].w;
    }
  };
  auto phase2 = [&](int ch0) {
#pragma unroll
    for (int q = 0; q < 4; ++q) {
      int c = cq + 16 * q;
      float t[8];
#pragma unroll
      for (int j = 0; j < 8; ++j) {
        int r = dk + j;
        t[j] = tile[r][c ^ ((r >> 5) << 2)] * scale;
      }
      uint2 o;
      o.x = f8pack4(t[0], t[1], t[2], t[3]);
      o.y = f8pack4(t[4], t[5], t[6], t[7]);
      *(uint2*)&d[(size_t)(ch0 + c) * R + by + dk] = o;
    }
  };

  wr_lds(v0);
  __syncthreads();
  phase2(bx);
  __syncthreads();
  wr_lds(v1);
  __syncthreads();
  phase2(bx + 64);
}

// ======== K1: router (blocks [0,nrouter)) + W1T transpose (rest) ========
__global__ void router_w1t_kernel(const float* __restrict__ x, const float* __restrict__ wsw,
                                  const float* __restrict__ bsw, int* __restrict__ routes,
                                  float* __restrict__ rpm, float* __restrict__ partial,
                                  fp8_t* __restrict__ xq8,
                                  const float* __restrict__ W1, fp8_t* __restrict__ W1T,
                                  int nrouter) {
  __shared__ float tile[128][65];
  const int bid = blockIdx.x;
  const int tid = threadIdx.x;
  if (bid >= nrouter) {
    const int tbid = bid - nrouter;
    const int z = tbid >> 8;
    const int rem = tbid & 255;
    transpose_tile128(W1 + (size_t)z * ((size_t)DDIM * FDIM),
                      W1T + (size_t)z * ((size_t)DDIM * FDIM),
                      DDIM, FDIM, (rem & 31) * 128, (rem >> 5) * 128, tile, tid, WSCALE);
  } else {
    const int rb = bid;
    const int wv = tid >> 6, lane = tid & 63;
    const int t = rb * 4 + wv;
    const float4* xr = (const float4*)(x + (size_t)t * DDIM);
    float4 xv[4];
    float a[8] = {0.f,0.f,0.f,0.f,0.f,0.f,0.f,0.f};
#pragma unroll
    for (int p = 0; p < 4; ++p) {
      xv[p] = xr[lane + p * 64];
#pragma unroll
      for (int j = 0; j < 4; ++j) {
        float v = ((const float*)&xv[p])[j];
        int d2 = (lane + p * 64) * 4 + j;
        const float4* wr = (const float4*)(wsw + d2 * 8);
        float4 w0 = wr[0], w1 = wr[1];
        a[0] += v * w0.x; a[1] += v * w0.y; a[2] += v * w0.z; a[3] += v * w0.w;
        a[4] += v * w1.x; a[5] += v * w1.y; a[6] += v * w1.z; a[7] += v * w1.w;
      }
    }
#pragma unroll
    for (int e = 0; e < 8; ++e) {
#pragma unroll
      for (int off = 32; off > 0; off >>= 1) a[e] += __shfl_xor(a[e], off);
      a[e] += bsw[e];
    }
    float m = a[0]; int arg = 0;
#pragma unroll
    for (int e = 1; e < 8; ++e) { if (a[e] > m) { m = a[e]; arg = e; } }
    float p8[8]; float s2 = 0.f;
#pragma unroll
    for (int e = 0; e < 8; ++e) { p8[e] = expf(a[e] - m); s2 += p8[e]; }
    float inv_s = 1.f / s2;   // = softmax max since p[arg]=1
    fp8_t* xqr = xq8 + (size_t)t * DDIM;
#pragma unroll
    for (int p = 0; p < 4; ++p) {
      int i4 = lane + p * 64;
      *(unsigned*)(xqr + (size_t)i4 * 4) = f8pack4(xv[p].x, xv[p].y, xv[p].z, xv[p].w);
    }
    float* pp = &tile[0][0];             // reuse LDS: [4][8]
    if (lane == 0) {
      routes[t] = arg;
      rpm[t] = inv_s;
#pragma unroll
      for (int e = 0; e < 8; ++e) pp[wv * 8 + e] = p8[e] * inv_s;
    }
    __syncthreads();
    if (tid < 8) {
      int e = tid;
      partial[(size_t)rb * 8 + e] = pp[0 + e] + pp[8 + e] + pp[16 + e] + pp[24 + e];
    }
  }
}

// ---- scan: PARALLEL prefix (Hillis-Steele over 256 thr x 8 experts) + dispatch + rps ----
__global__ void scan_kernel(const int* __restrict__ routes, int* __restrict__ inv,
                            int* __restrict__ counts_i, float* __restrict__ out_counts,
                            float* __restrict__ out_ndrop, int* __restrict__ drop_list,
                            int* __restrict__ ndrop_i, const float* __restrict__ partial,
                            float* __restrict__ out_rps) {
  __shared__ int sbuf[2][256][8];
  __shared__ int dropc;
  __shared__ float red[256];
  int tid = threadIdx.x;
  for (int i = tid; i < NEXP * CAP; i += 256) inv[i] = 0;   // zero (incl. padded tail)
  if (tid == 0) dropc = 0;
  int myr[32];
  int cnt[8] = {0,0,0,0,0,0,0,0};
  int tbase = tid * 32;
  for (int i = 0; i < 32; ++i) { int r = routes[tbase + i]; myr[i] = r; cnt[r]++; }
#pragma unroll
  for (int e = 0; e < 8; ++e) sbuf[0][tid][e] = cnt[e];
  __syncthreads();
  int cur = 0;
  for (int step = 1; step < 256; step <<= 1) {   // inclusive scan, 8 steps
#pragma unroll
    for (int e = 0; e < 8; ++e) {
      int v = sbuf[cur][tid][e];
      if (tid >= step) v += sbuf[cur][tid - step][e];
      sbuf[cur ^ 1][tid][e] = v;
    }
    __syncthreads();
    cur ^= 1;
  }
  int base[8];
#pragma unroll
  for (int e = 0; e < 8; ++e) base[e] = sbuf[cur][tid][e] - cnt[e];   // exclusive prefix
  for (int i = 0; i < 32; ++i) {
    int r = myr[i];
    int p = base[r]++;
    if (p < CAP) inv[r * CAP + p] = tbase + i;
    else         drop_list[atomicAdd(&dropc, 1)] = tbase + i;
  }
  if (tid < 8) {
    int c = min(sbuf[cur][255][tid], CAP);      // raw totals at last thread
    counts_i[tid] = c;
    out_counts[tid] = (float)c;
  }
  __syncthreads();
  if (tid == 0) {
    *ndrop_i = dropc;
    *out_ndrop = (float)dropc;
  }
  // deterministic route_prob_sums reduction
  {
    int e2 = tid & 7, j0 = tid >> 3;
    float s = 0.f;
    for (int j = j0; j < 2048; j += 32) s += partial[j * 8 + e2];
    red[tid] = s;
    __syncthreads();
    if (tid < 8) {
      float tt = 0.f;
      for (int k = 0; k < 32; ++k) tt += red[tid + 8 * k];
      out_rps[tid] = tt;
    }
  }
}

// ---------------- fill only dropped tokens: out[t] = x[t]*rpm[t] ----------------
__global__ void fill_dropped_kernel(const int* __restrict__ drop_list, const int* __restrict__ ndrop_i,
                                    const float* __restrict__ x, const float* __restrict__ rpm,
                                    float* __restrict__ outf) {
  int total = (*ndrop_i) * 256;    // float4s per dropped token row
  for (int i = blockIdx.x * blockDim.x + threadIdx.x; i < total; i += gridDim.x * blockDim.x) {
    int t = drop_list[i >> 8];
    int j = i & 255;
    float r = rpm[t];
    float4 v = ((const float4*)(x + (size_t)t * DDIM))[j];
    float4 o = {v.x * r, v.y * r, v.z * r, v.w * r};
    ((float4*)(outf + (size_t)t * DDIM))[j] = o;
  }
}

// ---------------- standalone transpose (only for nb<2 fallback) ----------------
__global__ void transpose_both_kernel(const float* __restrict__ W1, const float* __restrict__ W2,
                                      fp8_t* __restrict__ W1T, fp8_t* __restrict__ W2T,
                                      int nb, int e0) {
  __shared__ float tile[128][65];
  const int z = blockIdx.z;
  const int rem = blockIdx.x;          // 256 tiles per slice
  if (z < nb) {
    transpose_tile128(W1 + (size_t)(e0 + z) * ((size_t)DDIM * FDIM),
                      W1T + (size_t)z * ((size_t)DDIM * FDIM),
                      DDIM, FDIM, (rem & 31) * 128, (rem >> 5) * 128, tile, threadIdx.x, WSCALE);
  } else {
    transpose_tile128(W2 + (size_t)(e0 + z - nb) * ((size_t)FDIM * DDIM),
                      W2T + (size_t)(z - nb) * ((size_t)FDIM * DDIM),
                      FDIM, DDIM, (rem >> 5) * 128, (rem & 31) * 128, tile, threadIdx.x, WSCALE);
  }
}

// ====== MFMA GEMM (fp8 e4m3): 128x128, BK=32, 4 waves, 3-slot ring, depth-2 prefetch ======
// R17-proven ring schedule, currency switched to fp8: per tile-block LDS traffic
// 48KB->24KB, DMA 16->8KB; mfma_f32_16x16x32_fp8_fp8 (same K, same 8-K-contig/lane
// fragment shape as verified bf16 16x16x32; C/D layout dtype-independent m121-128).
// A slot 4KB [128 rows][32B] + B slot 4KB; NO swizzle (b64 frag reads are uniform
// 4-accesses/bank = structural floor; bank = (8r+2j+k)%32 covers all banks evenly).
// Per tile t: VMWAIT(2) [retires stage(t)=2 gloads; keeps stage(t+1)] -> s_barrier ->
// stage(t+2) [slot (t+2)%3==(t-1)%3: dead post-barrier] -> 8 ds_read_b64 + 16 MFMA.
// Weights pre-scaled x64 into e4m3 normal range; epilogue multiplies 1/64 pre-bias.
// MODE 1: A=W1T, B=xq8 gathered via inv -> relu(v/64+b1) -> h fp8
// MODE 2: A=W2T, B=hq                   -> (v/64+b2)*rpm scattered -> final f32
// MODE 1 extra: blocks flat<ntiles run one W2T 128x128 chunk after, reusing smem (33KB).
template <int KDIM, int MODE>
__launch_bounds__(256, 4)
__global__ void gemm_kernel(const fp8_t* __restrict__ Abase, const fp8_t* __restrict__ Bbase,
                            const int* __restrict__ inv, const int* __restrict__ counts_i,
                            const float* __restrict__ bias_all, const float* __restrict__ rpm,
                            void* __restrict__ outp, int e0,
                            const float* __restrict__ Wsrc, fp8_t* __restrict__ Wdst,
                            int ntiles) {
  constexpr int MDIM = (MODE == 1) ? FDIM : DDIM;
  constexpr int NT = KDIM / 32;
  constexpr int ABYTES = 4096;         // A region per slot (128 rows x 32B)
  constexpr int SLOT = 8192;           // + B region
  extern __shared__ __align__(16) char smem[];

  // T1: XCD-chunked bijective swizzle (nwg % 8 == 0 by construction)
  const int nx = gridDim.x, ny = gridDim.y;
  const int nwg = nx * ny * gridDim.z;
  const int flat = blockIdx.x + nx * (blockIdx.y + ny * blockIdx.z);
  const int nf = (flat & 7) * (nwg >> 3) + (flat >> 3);
  const int bx = nf % nx;
  const int tmp = nf / nx;
  const int by = tmp % ny, bz = tmp / ny;

  const int tid = threadIdx.x;
  const int e = e0 + bz;
  const int cnt = counts_i[e];
  const int c0 = bx * 128;
  const int m0 = by * 128;
  const bool doGemm = (c0 < cnt);      // uniform across block

  if (doGemm) {
    const fp8_t* A = Abase + (size_t)bz * ((size_t)MDIM * KDIM);
    const float* bias = bias_all + (size_t)e * MDIM;

    const int lane = tid & 63, w = tid >> 6;
    const int l15 = lane & 15, l4 = lane >> 4;
    const int wm = w >> 1, wn = w & 1;

    // ---- stage sources: thread tid covers row tid>>1, 16B-granule tid&1 ----
    const size_t aOff = (size_t)(m0 + (tid >> 1)) * KDIM + (tid & 1) * 16;
    const fp8_t* bp;
    {
      int c = tid >> 1;
      if (MODE == 1) {
        int tok = inv[e * CAP + c0 + c];   // zeroed tail -> token 0 (result unread)
        bp = Bbase + (size_t)tok * KDIM + (tid & 1) * 16;
      } else {
        bp = Bbase + (size_t)bz * ((size_t)CAP * KDIM) + (size_t)(c0 + c) * KDIM + (tid & 1) * 16;
      }
    }

    // ---- frag read offsets (b64; no swizzle needed) ----
    int aRd[4], bRd[4];
#pragma unroll
    for (int mi = 0; mi < 4; ++mi)
      aRd[mi] = (wm * 64 + mi * 16 + l15) * 32 + l4 * 8;
#pragma unroll
    for (int nj = 0; nj < 4; ++nj)
      bRd[nj] = ABYTES + (wn * 64 + nj * 16 + l15) * 32 + l4 * 8;

    auto stage = [&](int t) {
      char* s = smem + (t % 3) * SLOT + w * 1024;
      gload16(A + aOff + t * 32, s);
      gload16(bp + t * 32, s + ABYTES);
    };

    f32x4 acc[4][4];
#pragma unroll
    for (int i = 0; i < 4; ++i)
#pragma unroll
      for (int j = 0; j < 4; ++j) acc[i][j] = (f32x4){0.f, 0.f, 0.f, 0.f};

    // prologue: 2 tiles in flight
    stage(0); stage(1);

    for (int t = 0; t < NT; ++t) {
      if (t + 1 < NT) { VMWAIT(2); } else { VMWAIT(0); }   // retire exactly stage(t)
      BARR;                              // publish tile t to all waves
      if (t + 2 < NT) stage(t + 2);      // slot (t-1)%3: dead post-barrier
      const char* s = smem + (t % 3) * SLOT;
      long af[4], bf[4];
#pragma unroll
      for (int mi = 0; mi < 4; ++mi) af[mi] = *(const long*)(s + aRd[mi]);
#pragma unroll
      for (int nj = 0; nj < 4; ++nj) bf[nj] = *(const long*)(s + bRd[nj]);
      __builtin_amdgcn_s_setprio(1);
#pragma unroll
      for (int mi = 0; mi < 4; ++mi)
#pragma unroll
        for (int nj = 0; nj < 4; ++nj)
          acc[mi][nj] = __builtin_amdgcn_mfma_f32_16x16x32_fp8_fp8(af[mi], bf[nj], acc[mi][nj], 0, 0, 0);
      __builtin_amdgcn_s_setprio(0);
    }

    // ---- epilogue: D layout col=lane&15, row=(lane>>4)*4+reg [m89/m91, dtype-indep] ----
    if constexpr (MODE == 1) {
      fp8_t* h = (fp8_t*)outp + (size_t)bz * ((size_t)CAP * FDIM);
#pragma unroll
      for (int nj = 0; nj < 4; ++nj) {
        int c = c0 + wn * 64 + nj * 16 + l15;
        fp8_t* hrow = h + (size_t)c * FDIM;
#pragma unroll
        for (int mi = 0; mi < 4; ++mi) {
          int f = m0 + wm * 64 + mi * 16 + l4 * 4;
          const float4 bi = *(const float4*)&bias[f];
          f32x4 v = acc[mi][nj];
          float h0 = fmaxf(v[0] * INV_WSCALE + bi.x, 0.f);
          float h1 = fmaxf(v[1] * INV_WSCALE + bi.y, 0.f);
          float h2 = fmaxf(v[2] * INV_WSCALE + bi.z, 0.f);
          float h3 = fmaxf(v[3] * INV_WSCALE + bi.w, 0.f);
          *(unsigned*)&hrow[f] = f8pack4(h0, h1, h2, h3);
        }
      }
    } else {
      float* finalp = (float*)outp;
#pragma unroll
      for (int nj = 0; nj < 4; ++nj) {
        int c = c0 + wn * 64 + nj * 16 + l15;
        if (c < cnt) {
          int tok = inv[e * CAP + c];
          float r = rpm[tok];
          float* orow = finalp + (size_t)tok * DDIM;
#pragma unroll
          for (int mi = 0; mi < 4; ++mi) {
            int dd = m0 + wm * 64 + mi * 16 + l4 * 4;
            const float4 bi = *(const float4*)&bias[dd];
            f32x4 v = acc[mi][nj];
            float4 o;
            o.x = (v[0] * INV_WSCALE + bi.x) * r;
            o.y = (v[1] * INV_WSCALE + bi.y) * r;
            o.z = (v[2] * INV_WSCALE + bi.z) * r;
            o.w = (v[3] * INV_WSCALE + bi.w) * r;
            *(float4*)&orow[dd] = o;
          }
        }
      }
    }
  }

  // ---- interleaved W2T chunk (MODE 1 only): reuse smem as f32[128][65] ----
  if constexpr (MODE == 1) {
    if (Wsrc != nullptr && flat < ntiles) {
      if (doGemm) BARR;                 // all waves' ring ds_reads retired
      const int z2 = flat >> 8;
      const int rem = flat & 255;
      transpose_tile128(Wsrc + (size_t)z2 * ((size_t)FDIM * DDIM),
                        Wdst + (size_t)z2 * ((size_t)FDIM * DDIM),
                        FDIM, DDIM, (rem >> 5) * 128, (rem & 31) * 128,
                        (float(*)[65])smem, tid, WSCALE);
    }
  }
}

// ---------------- host launcher ----------------
extern "C" void kernel_launch(void* const* d_in, const int* in_sizes, int n_in,
                              void* d_out, int out_size, void* d_ws, size_t ws_size,
                              hipStream_t stream) {
  (void)in_sizes; (void)n_in; (void)out_size;
  const float* x   = (const float*)d_in[0];
  const float* wsw = (const float*)d_in[1];
  const float* bsw = (const float*)d_in[2];
  const float* W1  = (const float*)d_in[3];
  const float* b1  = (const float*)d_in[4];
  const float* W2  = (const float*)d_in[5];
  const float* b2  = (const float*)d_in[6];

  float* out_final  = (float*)d_out;            // [T][D]
  float* out_counts = out_final + 8388608;      // [8]
  float* out_rps    = out_final + 8388616;      // [8]
  float* out_ndrop  = out_final + 8388624;      // [1]
  float* out_rpm    = out_final + 8388625;      // [T] (output 5 of reference)

  char* ws = (char*)d_ws;
  size_t off = 0;
  auto carve = [&](size_t bytes) {
    char* p = ws + off;
    off += (bytes + 255) & ~(size_t)255;
    return p;
  };
  fp8_t*  xq8      = (fp8_t*) carve((size_t)T_TOK * DDIM);       // 8 MB
  int*    routes   = (int*)   carve((size_t)T_TOK * 4);
  int*    inv      = (int*)   carve((size_t)NEXP * CAP * 4);
  int*    counts_i = (int*)   carve((size_t)NEXP * 4);
  float*  partial  = (float*) carve((size_t)2048 * 8 * 4);
  int*    drop_list= (int*)   carve((size_t)T_TOK * 4);
  int*    ndrop_i  = (int*)   carve(256);
  size_t fixed = off;
  const size_t PER_E = 2 * (size_t)FDIM * DDIM + (size_t)CAP * FDIM;   // fp8: 16MB
  int nb = 8;
  while (nb > 1 && fixed + (size_t)nb * PER_E > ws_size) nb >>= 1;
  fp8_t* W1T = (fp8_t*)carve((size_t)nb * FDIM * DDIM);
  fp8_t* W2T = (fp8_t*)carve((size_t)nb * DDIM * FDIM);
  fp8_t* hq  = (fp8_t*)carve((size_t)nb * CAP * FDIM);

  const bool fuse = (nb >= 2);
  const int nrouter = T_TOK / 4;
  const int ntransK1 = fuse ? nb * 256 : 0;   // W1T tiles for first batch
  const int SMEM_G1 = 33280;                  // max(3*8192 ring, 128*65*4 transpose)
  const int SMEM_G2 = 3 * 8192;               // 24KB ring

  router_w1t_kernel<<<nrouter + ntransK1, 256, 0, stream>>>(
      x, wsw, bsw, routes, out_rpm, partial, xq8, W1, W1T, nrouter);
  scan_kernel<<<1, 256, 0, stream>>>(routes, inv, counts_i, out_counts, out_ndrop,
                                     drop_list, ndrop_i, partial, out_rps);
  fill_dropped_kernel<<<256, 256, 0, stream>>>(drop_list, ndrop_i, x, out_rpm, out_final);

  for (int e0 = 0; e0 < NEXP; e0 += nb) {
    if (e0 == 0 && fuse) {
      // GEMM1 with W2T chunks interleaved into the first nb*256 blocks
      gemm_kernel<DDIM, 1><<<dim3(CAP / 128, FDIM / 128, nb), 256, SMEM_G1, stream>>>(
          W1T, xq8, inv, counts_i, b1, nullptr, hq, e0, W2, W2T, nb * 256);
    } else {
      transpose_both_kernel<<<dim3(256, 1, 2 * nb), 256, 0, stream>>>(W1, W2, W1T, W2T, nb, e0);
      gemm_kernel<DDIM, 1><<<dim3(CAP / 128, FDIM / 128, nb), 256, SMEM_G1, stream>>>(
          W1T, xq8, inv, counts_i, b1, nullptr, hq, e0, nullptr, nullptr, 0);
    }
    gemm_kernel<FDIM, 2><<<dim3(CAP / 128, DDIM / 128, nb), 256, SMEM_G2, stream>>>(
        W2T, hq, inv, counts_i, b2, out_rpm, d_out, e0, nullptr, nullptr, 0);
  }
}